// Round 2
// baseline (178.156 us; speedup 1.0000x reference)
//
#include <hip/hip_runtime.h>
#include <hip/hip_bf16.h>
#include <cstdint>

#define EMBED   1024
#define NHEADS  16
#define HDIM    64
#define SEQ     2048
#define BSZ     2
#define MTOT    (BSZ*SEQ)   // 4096
#define NCLS    1000
#define NPAD    1024

typedef __attribute__((ext_vector_type(8))) short short8;
typedef __attribute__((ext_vector_type(4))) short short4v;
typedef __attribute__((ext_vector_type(4))) float float4v;

typedef __attribute__((address_space(3))) unsigned lds_uint;
typedef __attribute__((address_space(1))) const unsigned gbl_uint;

__device__ __forceinline__ void gl2lds16(const void* g, void* l) {
    __builtin_amdgcn_global_load_lds((gbl_uint*)g, (lds_uint*)l, 16, 0, 0);
}

__device__ __forceinline__ void storeC(float* p, float v) { *p = v; }
__device__ __forceinline__ void storeC(__hip_bfloat16* p, float v) { *p = __float2bfloat16(v); }

// ---------------------------------------------------------------------------
// Convert fp32 inputs to bf16 workspace copies; pad W_out to 1024 rows.
// Each thread handles one float4 (4 elements). Grid covers x | W_in | W_out_pad.
// ---------------------------------------------------------------------------
#define XN4  ((MTOT*EMBED)/4)    // 1,048,576
#define WN4  ((EMBED*EMBED)/4)   // 262,144
__global__ __launch_bounds__(256)
void conv_inputs(const float* __restrict__ x, const float* __restrict__ Win,
                 const float* __restrict__ Wout,
                 __hip_bfloat16* __restrict__ xb, __hip_bfloat16* __restrict__ Winb,
                 __hip_bfloat16* __restrict__ Woutb) {
    const long i4 = (long)blockIdx.x * 256 + threadIdx.x;  // float4 index
    float4v v;
    __hip_bfloat16* dst;
    if (i4 < XN4) {
        v = *(const float4v*)(x + i4 * 4);
        dst = xb + i4 * 4;
    } else if (i4 < XN4 + WN4) {
        const long j = i4 - XN4;
        v = *(const float4v*)(Win + j * 4);
        dst = Winb + j * 4;
    } else {
        const long j = i4 - XN4 - WN4;
        const int r = (int)((j * 4) >> 10);   // padded row
        if (r < NCLS) v = *(const float4v*)(Wout + j * 4);
        else          v = (float4v){0.f, 0.f, 0.f, 0.f};
        dst = Woutb + j * 4;
    }
    short4v o;
#pragma unroll
    for (int u = 0; u < 4; u++)
        ((__hip_bfloat16*)&o)[u] = __float2bfloat16(v[u]);
    *(short4v*)dst = o;
}

// ---------------------------------------------------------------------------
// GEMM: C[m][n] = sum_k A[m][k] * B[n][k] + bias[n]   (row-major, B^T input)
// 128x128 tile, BK=32, 4 waves, mfma_f32_16x16x32_bf16, global_load_lds w=16.
// A,B bf16; bias fp32; C store type templated (fp32 or bf16).
// M, N multiples of 128; K multiple of 32. Stores/bias guarded at n < nstore.
// ---------------------------------------------------------------------------
template <typename CT>
__global__ __launch_bounds__(256)
void gemm_bt_bias(const __hip_bfloat16* __restrict__ A,
                  const __hip_bfloat16* __restrict__ B,
                  const float* __restrict__ bias,
                  CT* __restrict__ C,
                  int K, int nstore, int cstride) {
    __shared__ __hip_bfloat16 As[128 * 32];
    __shared__ __hip_bfloat16 Bs[128 * 32];

    const int t    = threadIdx.x;
    const int bm   = blockIdx.x * 128;
    const int bn   = blockIdx.y * 128;
    const int wave = t >> 6, lane = t & 63;
    const int wm   = (wave & 1) * 64, wn = (wave >> 1) * 64;
    const int lrow = lane & 15, lq = lane >> 4;

    const long arow = bm + (t >> 2);
    const long brow = bn + (t >> 2);
    const int  kc8  = (t & 3) * 8;
    const __hip_bfloat16* Ab = A + arow * (long)K + kc8;
    const __hip_bfloat16* Bb = B + brow * (long)K + kc8;

    float4v acc[4][4];
#pragma unroll
    for (int i = 0; i < 4; i++)
#pragma unroll
        for (int j = 0; j < 4; j++) acc[i][j] = (float4v){0.f, 0.f, 0.f, 0.f};

    for (int k0 = 0; k0 < K; k0 += 32) {
        gl2lds16(Ab + k0,            (char*)As + t * 16);
        gl2lds16(Ab + 64 * K + k0,   (char*)As + t * 16 + 4096);
        gl2lds16(Bb + k0,            (char*)Bs + t * 16);
        gl2lds16(Bb + 64 * K + k0,   (char*)Bs + t * 16 + 4096);
        __syncthreads();

        short8 af[4], bf[4];
#pragma unroll
        for (int i = 0; i < 4; i++)
            af[i] = *(const short8*)((const char*)As + (wm + i * 16 + lrow) * 64 + lq * 16);
#pragma unroll
        for (int j = 0; j < 4; j++)
            bf[j] = *(const short8*)((const char*)Bs + (wn + j * 16 + lrow) * 64 + lq * 16);
#pragma unroll
        for (int i = 0; i < 4; i++)
#pragma unroll
            for (int j = 0; j < 4; j++)
                acc[i][j] = __builtin_amdgcn_mfma_f32_16x16x32_bf16(af[i], bf[j], acc[i][j], 0, 0, 0);
        __syncthreads();
    }

    // epilogue: C/D layout col=lane&15, row=lq*4+reg
    float bv[4];
#pragma unroll
    for (int j = 0; j < 4; j++) {
        const int gn = bn + wn + j * 16 + lrow;
        bv[j] = (gn < nstore) ? bias[gn] : 0.f;
    }

#pragma unroll
    for (int i = 0; i < 4; i++) {
        const int gm0 = bm + wm + i * 16 + lq * 4;
#pragma unroll
        for (int j = 0; j < 4; j++) {
            const int gn = bn + wn + j * 16 + lrow;
            if (gn < nstore) {
#pragma unroll
                for (int r = 0; r < 4; r++)
                    storeC(&C[(long)(gm0 + r) * cstride + gn], acc[i][j][r] + bv[j]);
            }
        }
    }
}

// ---------------------------------------------------------------------------
// Gram: G[bh][d1][d2] += sum over 128 rows of P[s][d1]*P[s][d2]  (fp32 atomics)
// ---------------------------------------------------------------------------
__global__ __launch_bounds__(256)
void gram_kernel(const __hip_bfloat16* __restrict__ P, float* __restrict__ G) {
    const int bh = blockIdx.x;       // 0..31
    const int ck = blockIdx.y;       // 0..15
    const int b = bh >> 4, h = bh & 15;
    const int row0 = b * SEQ + ck * 128;

    __shared__ float Pl[128][64];
    const int t = threadIdx.x;
#pragma unroll
    for (int it = 0; it < 4; it++) {
        const int ci = it * 256 + t;
        const int r = ci >> 3, c8 = (ci & 7) * 8;
        short8 v = *(const short8*)(P + (long)(row0 + r) * EMBED + h * HDIM + c8);
#pragma unroll
        for (int u = 0; u < 8; u++)
            Pl[r][c8 + u] = __bfloat162float(((const __hip_bfloat16*)&v)[u]);
    }
    __syncthreads();

    const int ty = t >> 4, tx = t & 15;
    float acc[4][4] = {};
    for (int k = 0; k < 128; k++) {
        float4v a  = *(const float4v*)&Pl[k][4 * ty];
        float4v bb = *(const float4v*)&Pl[k][4 * tx];
#pragma unroll
        for (int i = 0; i < 4; i++)
#pragma unroll
            for (int j = 0; j < 4; j++) acc[i][j] += a[i] * bb[j];
    }
    float* Gh = G + bh * 4096;
#pragma unroll
    for (int i = 0; i < 4; i++)
#pragma unroll
        for (int j = 0; j < 4; j++)
            atomicAdd(&Gh[(4 * ty + i) * 64 + 4 * tx + j], acc[i][j]);
}

// ---------------------------------------------------------------------------
// PV: V[m][h*64+c] = scale * sum_d P[m][h*64+d] * G[bh][d][c]   (V bf16)
// ---------------------------------------------------------------------------
__global__ __launch_bounds__(256)
void pv_kernel(const __hip_bfloat16* __restrict__ P, const float* __restrict__ G,
               __hip_bfloat16* __restrict__ V) {
    const int rt = blockIdx.x;   // 0..63
    const int h  = blockIdx.y;   // 0..15
    const int row0 = rt * 64;
    const int b = row0 >> 11;
    const float* Gh = G + (b * 16 + h) * 4096;

    __shared__ float Pl[64][65];
    __shared__ float Gl[64][64];
    const int t = threadIdx.x;

#pragma unroll
    for (int it = 0; it < 2; it++) {
        const int ci = it * 256 + t;
        const int r = ci >> 3, c8 = (ci & 7) * 8;
        short8 v = *(const short8*)(P + (long)(row0 + r) * EMBED + h * HDIM + c8);
#pragma unroll
        for (int u = 0; u < 8; u++)
            Pl[r][c8 + u] = __bfloat162float(((const __hip_bfloat16*)&v)[u]);
    }
#pragma unroll
    for (int it = 0; it < 4; it++) {
        const int ci = it * 256 + t;
        const int r = ci >> 4, c4 = (ci & 15) * 4;
        *(float4v*)&Gl[r][c4] = *(const float4v*)&Gh[r * 64 + c4];
    }
    __syncthreads();

    const int ty = t >> 4, tx = t & 15;
    float acc[4][4] = {};
    for (int k = 0; k < 64; k++) {
        const float a0 = Pl[4 * ty + 0][k];
        const float a1 = Pl[4 * ty + 1][k];
        const float a2 = Pl[4 * ty + 2][k];
        const float a3 = Pl[4 * ty + 3][k];
        float4v g = *(const float4v*)&Gl[k][4 * tx];
#pragma unroll
        for (int j = 0; j < 4; j++) {
            acc[0][j] += a0 * g[j];
            acc[1][j] += a1 * g[j];
            acc[2][j] += a2 * g[j];
            acc[3][j] += a3 * g[j];
        }
    }
    const float scale = 1.0f / 32.0f;  // 1/sqrt(EMBED)
#pragma unroll
    for (int i = 0; i < 4; i++) {
        const int gr = row0 + 4 * ty + i;
        short4v ov;
#pragma unroll
        for (int j = 0; j < 4; j++)
            ((__hip_bfloat16*)&ov)[j] = __float2bfloat16(acc[i][j] * scale);
        *(short4v*)(V + (long)gr * EMBED + h * HDIM + 4 * tx) = ov;
    }
}

// ---------------------------------------------------------------------------
extern "C" void kernel_launch(void* const* d_in, const int* in_sizes, int n_in,
                              void* d_out, int out_size, void* d_ws, size_t ws_size,
                              hipStream_t stream) {
    const float* x     = (const float*)d_in[0];
    const float* W_in  = (const float*)d_in[1];
    const float* b_in  = (const float*)d_in[2];
    const float* W_out = (const float*)d_in[3];
    const float* b_out = (const float*)d_in[4];
    float* out = (float*)d_out;

    char* ws = (char*)d_ws;
    __hip_bfloat16* xb    = (__hip_bfloat16*)(ws);                        // 8 MiB
    __hip_bfloat16* Winb  = (__hip_bfloat16*)(ws + (8u << 20));           // 2 MiB
    __hip_bfloat16* Woutb = (__hip_bfloat16*)(ws + (10u << 20));          // 2 MiB (padded 1024x1024)
    __hip_bfloat16* P     = (__hip_bfloat16*)(ws + (12u << 20));          // 8 MiB
    __hip_bfloat16* V     = (__hip_bfloat16*)(ws + (20u << 20));          // 8 MiB
    float*          G     = (float*)(ws + (28u << 20));                   // 512 KiB

    hipMemsetAsync(G, 0, 32 * 64 * 64 * sizeof(float), stream);
    conv_inputs<<<(XN4 + 2 * WN4) / 256, 256, 0, stream>>>(x, W_in, W_out, xb, Winb, Woutb);

    // P = x @ W_in^T + b_in   [4096 x 1024] bf16
    gemm_bt_bias<__hip_bfloat16><<<dim3(32, 8), 256, 0, stream>>>(xb, Winb, b_in, P, EMBED, NPAD, NPAD);
    // G[bh] = P_h^T P_h
    gram_kernel<<<dim3(32, 16), 256, 0, stream>>>(P, G);
    // V = scale * P_h G[bh]
    pv_kernel<<<dim3(64, 16), 256, 0, stream>>>(P, G, V);
    // out = V @ W_out^T + b_out   [4096 x 1000] fp32
    gemm_bt_bias<float><<<dim3(32, 8), 256, 0, stream>>>(V, Woutb, b_out, out, EMBED, NCLS, NCLS);
}

// Round 3
// 166.196 us; speedup vs baseline: 1.0720x; 1.0720x over previous
//
#include <hip/hip_runtime.h>
#include <hip/hip_bf16.h>
#include <cstdint>

#define EMBED   1024
#define NHEADS  16
#define HDIM    64
#define SEQ     2048
#define BSZ     2
#define MTOT    (BSZ*SEQ)   // 4096
#define NCLS    1000
#define NPAD    1024

typedef __attribute__((ext_vector_type(8))) short short8;
typedef __attribute__((ext_vector_type(4))) short short4v;
typedef __attribute__((ext_vector_type(4))) float float4v;

typedef __attribute__((address_space(3))) unsigned lds_uint;
typedef __attribute__((address_space(1))) const unsigned gbl_uint;

__device__ __forceinline__ void gl2lds16(const void* g, void* l) {
    __builtin_amdgcn_global_load_lds((gbl_uint*)g, (lds_uint*)l, 16, 0, 0);
}

__device__ __forceinline__ void storeC(float* p, float v) { *p = v; }
__device__ __forceinline__ void storeC(__hip_bfloat16* p, float v) { *p = __float2bfloat16(v); }

// ---------------------------------------------------------------------------
// Convert fp32 inputs to bf16 ws copies; pad W_out to 1024 rows; zero G.
// ---------------------------------------------------------------------------
#define XN4  ((MTOT*EMBED)/4)    // 1,048,576
#define WN4  ((EMBED*EMBED)/4)   // 262,144
#define GN4  (32*64*64/4)        // 32,768
__global__ __launch_bounds__(256)
void conv_inputs(const float* __restrict__ x, const float* __restrict__ Win,
                 const float* __restrict__ Wout,
                 __hip_bfloat16* __restrict__ xb, __hip_bfloat16* __restrict__ Winb,
                 __hip_bfloat16* __restrict__ Woutb, float* __restrict__ G) {
    const long i4 = (long)blockIdx.x * 256 + threadIdx.x;  // float4 index
    if (i4 < GN4)
        *(float4v*)(G + i4 * 4) = (float4v){0.f, 0.f, 0.f, 0.f};
    float4v v;
    __hip_bfloat16* dst;
    if (i4 < XN4) {
        v = *(const float4v*)(x + i4 * 4);
        dst = xb + i4 * 4;
    } else if (i4 < XN4 + WN4) {
        const long j = i4 - XN4;
        v = *(const float4v*)(Win + j * 4);
        dst = Winb + j * 4;
    } else {
        const long j = i4 - XN4 - WN4;
        const int r = (int)((j * 4) >> 10);   // padded row
        if (r < NCLS) v = *(const float4v*)(Wout + j * 4);
        else          v = (float4v){0.f, 0.f, 0.f, 0.f};
        dst = Woutb + j * 4;
    }
    short4v o;
#pragma unroll
    for (int u = 0; u < 4; u++)
        ((__hip_bfloat16*)&o)[u] = __float2bfloat16(v[u]);
    *(short4v*)dst = o;
}

// ---------------------------------------------------------------------------
// GEMM: C[m][n] = sum_k A[m][k]*B[n][k] + bias[n]  (row-major, B^T input)
// 128x128 tile, BK=64 (128B LDS rows), XOR-swizzled LDS (slot = chunk^(row&7))
// so ds_read_b128 fragment reads are bank-conflict-free while global_load_lds
// dests stay wave-contiguous. mfma_f32_16x16x32_bf16, 4 waves.
// B batch-select: B += (bm>>11)*bstride  (0 for shared B).
// ---------------------------------------------------------------------------
template <typename CT>
__global__ __launch_bounds__(256)
void gemm_bt_bias(const __hip_bfloat16* __restrict__ A,
                  const __hip_bfloat16* __restrict__ B,
                  const float* __restrict__ bias,
                  CT* __restrict__ C,
                  int K, int nstore, int cstride, long bstride) {
    __shared__ __hip_bfloat16 As[128 * 64];   // 16 KiB, swizzled
    __shared__ __hip_bfloat16 Bs[128 * 64];   // 16 KiB, swizzled

    const int t    = threadIdx.x;
    const int bm   = blockIdx.x * 128;
    const int bn   = blockIdx.y * 128;
    const __hip_bfloat16* Bb = B + (long)(bm >> 11) * bstride;
    const int wave = t >> 6, lane = t & 63;
    const int wm   = (wave & 1) * 64, wn = (wave >> 1) * 64;
    const int lrow = lane & 15, lq = lane >> 4;

    // staging map: instr i stages chunk ci = i*256+t (1024 chunks of 16B).
    // LDS slot ci (wave-contiguous); holds global (row=ci>>3, chunk c=(ci&7)^(row&7))
    int srow[4], scol[4];
#pragma unroll
    for (int i = 0; i < 4; i++) {
        const int ci = i * 256 + t;
        const int r  = ci >> 3;
        srow[i] = r;
        scol[i] = ((ci & 7) ^ (r & 7)) * 8;   // element offset within 64-k row
    }

    float4v acc[4][4];
#pragma unroll
    for (int i = 0; i < 4; i++)
#pragma unroll
        for (int j = 0; j < 4; j++) acc[i][j] = (float4v){0.f, 0.f, 0.f, 0.f};

    for (int k0 = 0; k0 < K; k0 += 64) {
#pragma unroll
        for (int i = 0; i < 4; i++)
            gl2lds16(A  + (long)(bm + srow[i]) * K + k0 + scol[i],
                     (char*)As + (i * 256 + t) * 16);
#pragma unroll
        for (int i = 0; i < 4; i++)
            gl2lds16(Bb + (long)(bn + srow[i]) * K + k0 + scol[i],
                     (char*)Bs + (i * 256 + t) * 16);
        __syncthreads();

#pragma unroll
        for (int kk = 0; kk < 2; kk++) {
            short8 af[4], bf[4];
#pragma unroll
            for (int i = 0; i < 4; i++) {
                const int row = wm + i * 16 + lrow;
                const int sc  = (kk * 4 + lq) ^ (row & 7);
                af[i] = *(const short8*)(As + row * 64 + sc * 8);
            }
#pragma unroll
            for (int j = 0; j < 4; j++) {
                const int row = wn + j * 16 + lrow;
                const int sc  = (kk * 4 + lq) ^ (row & 7);
                bf[j] = *(const short8*)(Bs + row * 64 + sc * 8);
            }
#pragma unroll
            for (int i = 0; i < 4; i++)
#pragma unroll
                for (int j = 0; j < 4; j++)
                    acc[i][j] = __builtin_amdgcn_mfma_f32_16x16x32_bf16(af[i], bf[j], acc[i][j], 0, 0, 0);
        }
        __syncthreads();
    }

    // epilogue: C/D layout col=lane&15, row=lq*4+reg
    float bv[4];
#pragma unroll
    for (int j = 0; j < 4; j++) {
        const int gn = bn + wn + j * 16 + lrow;
        bv[j] = (gn < nstore) ? bias[gn] : 0.f;
    }
#pragma unroll
    for (int i = 0; i < 4; i++) {
        const int gm0 = bm + wm + i * 16 + lq * 4;
#pragma unroll
        for (int j = 0; j < 4; j++) {
            const int gn = bn + wn + j * 16 + lrow;
            if (gn < nstore) {
#pragma unroll
                for (int r = 0; r < 4; r++)
                    storeC(&C[(long)(gm0 + r) * cstride + gn], acc[i][j][r] + bv[j]);
            }
        }
    }
}

// ---------------------------------------------------------------------------
// Gram: G[bh][d1][d2] += sum over 128 rows of P[s][d1]*P[s][d2]  (fp32 atomics)
// ---------------------------------------------------------------------------
__global__ __launch_bounds__(256)
void gram_kernel(const __hip_bfloat16* __restrict__ P, float* __restrict__ G) {
    const int bh = blockIdx.x;       // 0..31
    const int ck = blockIdx.y;       // 0..15
    const int b = bh >> 4, h = bh & 15;
    const int row0 = b * SEQ + ck * 128;

    __shared__ float Pl[128][64];
    const int t = threadIdx.x;
#pragma unroll
    for (int it = 0; it < 4; it++) {
        const int ci = it * 256 + t;
        const int r = ci >> 3, c8 = (ci & 7) * 8;
        short8 v = *(const short8*)(P + (long)(row0 + r) * EMBED + h * HDIM + c8);
#pragma unroll
        for (int u = 0; u < 8; u++)
            Pl[r][c8 + u] = __bfloat162float(((const __hip_bfloat16*)&v)[u]);
    }
    __syncthreads();

    const int ty = t >> 4, tx = t & 15;
    float acc[4][4] = {};
    for (int k = 0; k < 128; k++) {
        float4v a  = *(const float4v*)&Pl[k][4 * ty];
        float4v bb = *(const float4v*)&Pl[k][4 * tx];
#pragma unroll
        for (int i = 0; i < 4; i++)
#pragma unroll
            for (int j = 0; j < 4; j++) acc[i][j] += a[i] * bb[j];
    }
    float* Gh = G + bh * 4096;
#pragma unroll
    for (int i = 0; i < 4; i++)
#pragma unroll
        for (int j = 0; j < 4; j++)
            atomicAdd(&Gh[(4 * ty + i) * 64 + 4 * tx + j], acc[i][j]);
}

// ---------------------------------------------------------------------------
// Weff: WeffT[b][n][64h+d1] = scale * sum_d Wout[n][64h+d] * G[b,h][d][d1]
// (G symmetric). GEMM2 then computes out = P @ WeffT^T + b_out. Kills V.
// ---------------------------------------------------------------------------
__global__ __launch_bounds__(256)
void weff_kernel(const __hip_bfloat16* __restrict__ Woutb, const float* __restrict__ G,
                 __hip_bfloat16* __restrict__ WeffT) {
    const int n0 = blockIdx.x * 64;  // row tile within padded 1024
    const int h  = blockIdx.y;
    const int b  = blockIdx.z;
    const float* Gh = G + (b * 16 + h) * 4096;

    __shared__ float Wl[64][65];
    __shared__ float Gl[64][64];
    const int t = threadIdx.x;

#pragma unroll
    for (int it = 0; it < 2; it++) {           // Wout slice: 64x64 bf16 -> f32
        const int ci = it * 256 + t;
        const int r = ci >> 3, c8 = (ci & 7) * 8;
        short8 v = *(const short8*)(Woutb + (long)(n0 + r) * EMBED + h * HDIM + c8);
#pragma unroll
        for (int u = 0; u < 8; u++)
            Wl[r][c8 + u] = __bfloat162float(((const __hip_bfloat16*)&v)[u]);
    }
#pragma unroll
    for (int it = 0; it < 4; it++) {           // G: 64x64 f32
        const int ci = it * 256 + t;
        const int r = ci >> 4, c4 = (ci & 15) * 4;
        *(float4v*)&Gl[r][c4] = *(const float4v*)&Gh[r * 64 + c4];
    }
    __syncthreads();

    const int ty = t >> 4, tx = t & 15;
    float acc[4][4] = {};
    for (int k = 0; k < 64; k++) {
        const float a0 = Wl[4 * ty + 0][k];
        const float a1 = Wl[4 * ty + 1][k];
        const float a2 = Wl[4 * ty + 2][k];
        const float a3 = Wl[4 * ty + 3][k];
        float4v g = *(const float4v*)&Gl[k][4 * tx];
#pragma unroll
        for (int j = 0; j < 4; j++) {
            acc[0][j] += a0 * g[j];
            acc[1][j] += a1 * g[j];
            acc[2][j] += a2 * g[j];
            acc[3][j] += a3 * g[j];
        }
    }
    const float scale = 1.0f / 32.0f;  // 1/sqrt(EMBED)
    __hip_bfloat16* Wt = WeffT + (long)b * EMBED * NPAD;
#pragma unroll
    for (int i = 0; i < 4; i++) {
        const int gr = n0 + 4 * ty + i;
        short4v ov;
#pragma unroll
        for (int j = 0; j < 4; j++)
            ((__hip_bfloat16*)&ov)[j] = __float2bfloat16(acc[i][j] * scale);
        *(short4v*)(Wt + (long)gr * EMBED + h * HDIM + 4 * tx) = ov;
    }
}

// ---------------------------------------------------------------------------
extern "C" void kernel_launch(void* const* d_in, const int* in_sizes, int n_in,
                              void* d_out, int out_size, void* d_ws, size_t ws_size,
                              hipStream_t stream) {
    const float* x     = (const float*)d_in[0];
    const float* W_in  = (const float*)d_in[1];
    const float* b_in  = (const float*)d_in[2];
    const float* W_out = (const float*)d_in[3];
    const float* b_out = (const float*)d_in[4];
    float* out = (float*)d_out;

    char* ws = (char*)d_ws;
    __hip_bfloat16* xb    = (__hip_bfloat16*)(ws);                 // 8 MiB
    __hip_bfloat16* Winb  = (__hip_bfloat16*)(ws + (8u  << 20));   // 2 MiB
    __hip_bfloat16* Woutb = (__hip_bfloat16*)(ws + (10u << 20));   // 2 MiB (padded 1024x1024)
    __hip_bfloat16* P     = (__hip_bfloat16*)(ws + (12u << 20));   // 8 MiB
    float*          G     = (float*)(ws + (20u << 20));            // 512 KiB
    __hip_bfloat16* WeffT = (__hip_bfloat16*)(ws + (21u << 20));   // 4 MiB (2 batches)

    // 1) fp32->bf16 converts, W_out pad, G zero
    conv_inputs<<<(XN4 + 2 * WN4) / 256, 256, 0, stream>>>(x, W_in, W_out, xb, Winb, Woutb, G);
    // 2) P = x @ W_in^T + b_in   [4096 x 1024] bf16
    gemm_bt_bias<__hip_bfloat16><<<dim3(32, 8), 256, 0, stream>>>(xb, Winb, b_in, P, EMBED, NPAD, NPAD, 0);
    // 3) G[bh] = P_h^T P_h
    gram_kernel<<<dim3(32, 16), 256, 0, stream>>>(P, G);
    // 4) WeffT[b] = scale * (G . Wout^T) per head block
    weff_kernel<<<dim3(16, 16, 2), 256, 0, stream>>>(Woutb, G, WeffT);
    // 5) out = P @ WeffT^T + b_out   [4096 x 1000] fp32, batch-strided B
    gemm_bt_bias<float><<<dim3(32, 8), 256, 0, stream>>>(P, WeffT, b_out, out, EMBED, NCLS, NCLS, (long)EMBED * NPAD);
}

// Round 4
// 160.851 us; speedup vs baseline: 1.1076x; 1.0332x over previous
//
#include <hip/hip_runtime.h>
#include <hip/hip_bf16.h>
#include <cstdint>

#define EMBED   1024
#define NHEADS  16
#define HDIM    64
#define SEQ     2048
#define BSZ     2
#define MTOT    (BSZ*SEQ)   // 4096
#define NCLS    1000
#define NPAD    1024

typedef __attribute__((ext_vector_type(8))) short short8;
typedef __attribute__((ext_vector_type(4))) short short4v;
typedef __attribute__((ext_vector_type(4))) float float4v;

typedef __attribute__((address_space(3))) unsigned lds_uint;
typedef __attribute__((address_space(1))) const unsigned gbl_uint;

__device__ __forceinline__ void gl2lds16(const void* g, void* l) {
    __builtin_amdgcn_global_load_lds((gbl_uint*)g, (lds_uint*)l, 16, 0, 0);
}

#define WAITVM8() asm volatile("s_waitcnt vmcnt(8)" ::: "memory")
#define WAITVM0() asm volatile("s_waitcnt vmcnt(0)" ::: "memory")
#define BAR()     asm volatile("s_barrier" ::: "memory")

__device__ __forceinline__ void storeC(float* p, float v) { *p = v; }
__device__ __forceinline__ void storeC(__hip_bfloat16* p, float v) { *p = __float2bfloat16(v); }

// ---------------------------------------------------------------------------
// Convert fp32 inputs to bf16 ws copies; pad W_out to 1024 rows; zero G.
// ---------------------------------------------------------------------------
#define XN4  ((MTOT*EMBED)/4)    // 1,048,576
#define WN4  ((EMBED*EMBED)/4)   // 262,144
#define GN4  (32*64*64/4)        // 32,768
__global__ __launch_bounds__(256)
void conv_inputs(const float* __restrict__ x, const float* __restrict__ Win,
                 const float* __restrict__ Wout,
                 __hip_bfloat16* __restrict__ xb, __hip_bfloat16* __restrict__ Winb,
                 __hip_bfloat16* __restrict__ Woutb, float* __restrict__ G) {
    const long i4 = (long)blockIdx.x * 256 + threadIdx.x;  // float4 index
    if (i4 < GN4)
        *(float4v*)(G + i4 * 4) = (float4v){0.f, 0.f, 0.f, 0.f};
    float4v v;
    __hip_bfloat16* dst;
    if (i4 < XN4) {
        v = *(const float4v*)(x + i4 * 4);
        dst = xb + i4 * 4;
    } else if (i4 < XN4 + WN4) {
        const long j = i4 - XN4;
        v = *(const float4v*)(Win + j * 4);
        dst = Winb + j * 4;
    } else {
        const long j = i4 - XN4 - WN4;
        const int r = (int)((j * 4) >> 10);   // padded row
        if (r < NCLS) v = *(const float4v*)(Wout + j * 4);
        else          v = (float4v){0.f, 0.f, 0.f, 0.f};
        dst = Woutb + j * 4;
    }
    short4v o;
#pragma unroll
    for (int u = 0; u < 4; u++)
        ((__hip_bfloat16*)&o)[u] = __float2bfloat16(v[u]);
    *(short4v*)dst = o;
}

// ---------------------------------------------------------------------------
// GEMM: C[m][n] = sum_k A[m][k]*B[n][k] + bias[n]  (row-major, B^T input)
// 128x128 tile, BK=64, XOR-swizzled LDS, DOUBLE-BUFFERED staging with raw
// s_barrier + s_waitcnt vmcnt(8): tile k+1's global_load_lds stay in flight
// across the barrier while tile k computes. 1 block/CU -> this hides the
// staging latency that __syncthreads' vmcnt(0) drain exposed.
// ---------------------------------------------------------------------------
template <typename CT>
__global__ __launch_bounds__(256)
void gemm_bt_bias(const __hip_bfloat16* __restrict__ A,
                  const __hip_bfloat16* __restrict__ B,
                  const float* __restrict__ bias,
                  CT* __restrict__ C,
                  int K, int nstore, int cstride, long bstride) {
    __shared__ __hip_bfloat16 As[2][128 * 64];   // 2 x 16 KiB, swizzled
    __shared__ __hip_bfloat16 Bs[2][128 * 64];

    const int t    = threadIdx.x;
    const int bm   = blockIdx.x * 128;
    const int bn   = blockIdx.y * 128;
    const __hip_bfloat16* Bb = B + (long)(bm >> 11) * bstride;
    const int wave = t >> 6, lane = t & 63;
    const int wm   = (wave & 1) * 64, wn = (wave >> 1) * 64;
    const int lrow = lane & 15, lq = lane >> 4;

    // staging map: chunk ci = i*256+t; LDS slot ci holds global
    // (row = ci>>3, k-chunk = (ci&7)^(row&7))  [16B chunks, 8 per 64-k row]
    int srow[4], scol[4];
#pragma unroll
    for (int i = 0; i < 4; i++) {
        const int ci = i * 256 + t;
        const int r  = ci >> 3;
        srow[i] = r;
        scol[i] = ((ci & 7) ^ (r & 7)) * 8;
    }
    const __hip_bfloat16* Arow[4];
    const __hip_bfloat16* Brow[4];
#pragma unroll
    for (int i = 0; i < 4; i++) {
        Arow[i] = A  + (long)(bm + srow[i]) * K + scol[i];
        Brow[i] = Bb + (long)(bn + srow[i]) * K + scol[i];
    }

    float4v acc[4][4];
#pragma unroll
    for (int i = 0; i < 4; i++)
#pragma unroll
        for (int j = 0; j < 4; j++) acc[i][j] = (float4v){0.f, 0.f, 0.f, 0.f};

    const int nIter = K >> 6;

    // preload tile 0 into buffer 0
#pragma unroll
    for (int i = 0; i < 4; i++)
        gl2lds16(Arow[i], (char*)As[0] + (i * 256 + t) * 16);
#pragma unroll
    for (int i = 0; i < 4; i++)
        gl2lds16(Brow[i], (char*)Bs[0] + (i * 256 + t) * 16);

    for (int it = 0; it < nIter; ++it) {
        const int cur = it & 1, nxt = cur ^ 1;
        if (it + 1 < nIter) {
            const int k0 = (it + 1) << 6;
#pragma unroll
            for (int i = 0; i < 4; i++)
                gl2lds16(Arow[i] + k0, (char*)As[nxt] + (i * 256 + t) * 16);
#pragma unroll
            for (int i = 0; i < 4; i++)
                gl2lds16(Brow[i] + k0, (char*)Bs[nxt] + (i * 256 + t) * 16);
            WAITVM8();   // current tile's 8 loads done; prefetch in flight
        } else {
            WAITVM0();
        }
        BAR();           // tile `cur` fully staged for all waves

        const __hip_bfloat16* Ac = As[cur];
        const __hip_bfloat16* Bc = Bs[cur];
#pragma unroll
        for (int kk = 0; kk < 2; kk++) {
            short8 af[4], bf[4];
#pragma unroll
            for (int i = 0; i < 4; i++) {
                const int row = wm + i * 16 + lrow;
                const int sc  = (kk * 4 + lq) ^ (row & 7);
                af[i] = *(const short8*)(Ac + row * 64 + sc * 8);
            }
#pragma unroll
            for (int j = 0; j < 4; j++) {
                const int row = wn + j * 16 + lrow;
                const int sc  = (kk * 4 + lq) ^ (row & 7);
                bf[j] = *(const short8*)(Bc + row * 64 + sc * 8);
            }
#pragma unroll
            for (int i = 0; i < 4; i++)
#pragma unroll
                for (int j = 0; j < 4; j++)
                    acc[i][j] = __builtin_amdgcn_mfma_f32_16x16x32_bf16(af[i], bf[j], acc[i][j], 0, 0, 0);
        }
        BAR();           // all waves done reading `cur` before it's overwritten
    }

    // epilogue: C/D layout col=lane&15, row=lq*4+reg
    float bv[4];
#pragma unroll
    for (int j = 0; j < 4; j++) {
        const int gn = bn + wn + j * 16 + lrow;
        bv[j] = (gn < nstore) ? bias[gn] : 0.f;
    }
#pragma unroll
    for (int i = 0; i < 4; i++) {
        const int gm0 = bm + wm + i * 16 + lq * 4;
#pragma unroll
        for (int j = 0; j < 4; j++) {
            const int gn = bn + wn + j * 16 + lrow;
            if (gn < nstore) {
#pragma unroll
                for (int r = 0; r < 4; r++)
                    storeC(&C[(long)(gm0 + r) * cstride + gn], acc[i][j][r] + bv[j]);
            }
        }
    }
}

// ---------------------------------------------------------------------------
// Gram: G[bh][d1][d2] += sum over 128 rows of P[s][d1]*P[s][d2]  (fp32 atomics)
// ---------------------------------------------------------------------------
__global__ __launch_bounds__(256)
void gram_kernel(const __hip_bfloat16* __restrict__ P, float* __restrict__ G) {
    const int bh = blockIdx.x;       // 0..31
    const int ck = blockIdx.y;       // 0..15
    const int b = bh >> 4, h = bh & 15;
    const int row0 = b * SEQ + ck * 128;

    __shared__ float Pl[128][64];
    const int t = threadIdx.x;
#pragma unroll
    for (int it = 0; it < 4; it++) {
        const int ci = it * 256 + t;
        const int r = ci >> 3, c8 = (ci & 7) * 8;
        short8 v = *(const short8*)(P + (long)(row0 + r) * EMBED + h * HDIM + c8);
#pragma unroll
        for (int u = 0; u < 8; u++)
            Pl[r][c8 + u] = __bfloat162float(((const __hip_bfloat16*)&v)[u]);
    }
    __syncthreads();

    const int ty = t >> 4, tx = t & 15;
    float acc[4][4] = {};
    for (int k = 0; k < 128; k++) {
        float4v a  = *(const float4v*)&Pl[k][4 * ty];
        float4v bb = *(const float4v*)&Pl[k][4 * tx];
#pragma unroll
        for (int i = 0; i < 4; i++)
#pragma unroll
            for (int j = 0; j < 4; j++) acc[i][j] += a[i] * bb[j];
    }
    float* Gh = G + bh * 4096;
#pragma unroll
    for (int i = 0; i < 4; i++)
#pragma unroll
        for (int j = 0; j < 4; j++)
            atomicAdd(&Gh[(4 * ty + i) * 64 + 4 * tx + j], acc[i][j]);
}

// ---------------------------------------------------------------------------
// Weff: WeffT[b][n][64h+d1] = scale * sum_d Wout[n][64h+d] * G[b,h][d][d1]
// (G symmetric). GEMM2 computes out = P @ WeffT^T + b_out.
// ---------------------------------------------------------------------------
__global__ __launch_bounds__(256)
void weff_kernel(const __hip_bfloat16* __restrict__ Woutb, const float* __restrict__ G,
                 __hip_bfloat16* __restrict__ WeffT) {
    const int n0 = blockIdx.x * 64;
    const int h  = blockIdx.y;
    const int b  = blockIdx.z;
    const float* Gh = G + (b * 16 + h) * 4096;

    __shared__ float Wl[64][65];
    __shared__ float Gl[64][64];
    const int t = threadIdx.x;

#pragma unroll
    for (int it = 0; it < 2; it++) {
        const int ci = it * 256 + t;
        const int r = ci >> 3, c8 = (ci & 7) * 8;
        short8 v = *(const short8*)(Woutb + (long)(n0 + r) * EMBED + h * HDIM + c8);
#pragma unroll
        for (int u = 0; u < 8; u++)
            Wl[r][c8 + u] = __bfloat162float(((const __hip_bfloat16*)&v)[u]);
    }
#pragma unroll
    for (int it = 0; it < 4; it++) {
        const int ci = it * 256 + t;
        const int r = ci >> 4, c4 = (ci & 15) * 4;
        *(float4v*)&Gl[r][c4] = *(const float4v*)&Gh[r * 64 + c4];
    }
    __syncthreads();

    const int ty = t >> 4, tx = t & 15;
    float acc[4][4] = {};
    for (int k = 0; k < 64; k++) {
        const float a0 = Wl[4 * ty + 0][k];
        const float a1 = Wl[4 * ty + 1][k];
        const float a2 = Wl[4 * ty + 2][k];
        const float a3 = Wl[4 * ty + 3][k];
        float4v g = *(const float4v*)&Gl[k][4 * tx];
#pragma unroll
        for (int j = 0; j < 4; j++) {
            acc[0][j] += a0 * g[j];
            acc[1][j] += a1 * g[j];
            acc[2][j] += a2 * g[j];
            acc[3][j] += a3 * g[j];
        }
    }
    const float scale = 1.0f / 32.0f;  // 1/sqrt(EMBED)
    __hip_bfloat16* Wt = WeffT + (long)b * EMBED * NPAD;
#pragma unroll
    for (int i = 0; i < 4; i++) {
        const int gr = n0 + 4 * ty + i;
        short4v ov;
#pragma unroll
        for (int j = 0; j < 4; j++)
            ((__hip_bfloat16*)&ov)[j] = __float2bfloat16(acc[i][j] * scale);
        *(short4v*)(Wt + (long)gr * EMBED + h * HDIM + 4 * tx) = ov;
    }
}

// ---------------------------------------------------------------------------
extern "C" void kernel_launch(void* const* d_in, const int* in_sizes, int n_in,
                              void* d_out, int out_size, void* d_ws, size_t ws_size,
                              hipStream_t stream) {
    const float* x     = (const float*)d_in[0];
    const float* W_in  = (const float*)d_in[1];
    const float* b_in  = (const float*)d_in[2];
    const float* W_out = (const float*)d_in[3];
    const float* b_out = (const float*)d_in[4];
    float* out = (float*)d_out;

    char* ws = (char*)d_ws;
    __hip_bfloat16* xb    = (__hip_bfloat16*)(ws);                 // 8 MiB
    __hip_bfloat16* Winb  = (__hip_bfloat16*)(ws + (8u  << 20));   // 2 MiB
    __hip_bfloat16* Woutb = (__hip_bfloat16*)(ws + (10u << 20));   // 2 MiB (padded 1024x1024)
    __hip_bfloat16* P     = (__hip_bfloat16*)(ws + (12u << 20));   // 8 MiB
    float*          G     = (float*)(ws + (20u << 20));            // 512 KiB
    __hip_bfloat16* WeffT = (__hip_bfloat16*)(ws + (21u << 20));   // 4 MiB (2 batches)

    // 1) fp32->bf16 converts, W_out pad, G zero
    conv_inputs<<<(XN4 + 2 * WN4) / 256, 256, 0, stream>>>(x, W_in, W_out, xb, Winb, Woutb, G);
    // 2) P = x @ W_in^T + b_in   [4096 x 1024] bf16
    gemm_bt_bias<__hip_bfloat16><<<dim3(32, 8), 256, 0, stream>>>(xb, Winb, b_in, P, EMBED, NPAD, NPAD, 0);
    // 3) G[bh] = P_h^T P_h
    gram_kernel<<<dim3(32, 16), 256, 0, stream>>>(P, G);
    // 4) WeffT[b] = scale * (G . Wout^T) per head block
    weff_kernel<<<dim3(16, 16, 2), 256, 0, stream>>>(Woutb, G, WeffT);
    // 5) out = P @ WeffT^T + b_out   [4096 x 1000] fp32, batch-strided B
    gemm_bt_bias<float><<<dim3(32, 8), 256, 0, stream>>>(P, WeffT, b_out, out, EMBED, NCLS, NCLS, (long)EMBED * NPAD);
}